// Round 1
// baseline (6660.744 us; speedup 1.0000x reference)
//
#include <hip/hip_runtime.h>

typedef __bf16 bf8 __attribute__((ext_vector_type(8)));
typedef float  f4  __attribute__((ext_vector_type(4)));

// ---------------- pillar stage ----------------

__global__ __launch_bounds__(256) void k_cell(const float* __restrict__ x, int* __restrict__ cellArr,
                                              float* __restrict__ cnt, float* __restrict__ cent){
  int p = blockIdx.x*256 + threadIdx.x;            // 65536 points
  float x0 = x[p*3+0], x1 = x[p*3+1], x2 = x[p*3+2];
  // p_perm = (x1, x0, x2); yx = clip(p_perm[1:]+1, 0, 1.99) = (x0+1, x2+1)
  float y0 = fminf(fmaxf(x0 + 1.0f, 0.0f), 1.99f);
  float y1 = fminf(fmaxf(x2 + 1.0f, 0.0f), 1.99f);
  int i0 = (int)floorf(y0 / 0.2f);
  int i1 = (int)floorf(y1 / 0.2f);
  int b = p >> 11;                                  // N=2048 points per batch
  int cell = b*100 + i0*10 + i1;
  cellArr[p] = cell;
  atomicAdd(&cnt[cell], 1.0f);
  atomicAdd(&cent[cell*3+0], x1);
  atomicAdd(&cent[cell*3+1], x0);
  atomicAdd(&cent[cell*3+2], x2);
}

__global__ void k_centdiv(float* cent, const float* cnt){
  int i = blockIdx.x*256 + threadIdx.x;
  if (i < 3200*3) cent[i] /= fmaxf(cnt[i/3], 1.0f);
}

__global__ __launch_bounds__(256) void k_pointmlp(const float* __restrict__ x,
    const float* __restrict__ W1, const float* __restrict__ W2, const float* __restrict__ W3,
    const float* __restrict__ cent, const int* __restrict__ cellArr,
    __bf16* __restrict__ A2, float* __restrict__ pooled){
  __shared__ float w1s[6*32];
  __shared__ float w2s[32*64];
  __shared__ float w3s[64*128];
  int tid = threadIdx.x;
  for (int i = tid; i < 192;  i += 256) w1s[i] = W1[i];
  for (int i = tid; i < 2048; i += 256) w2s[i] = W2[i];
  for (int i = tid; i < 8192; i += 256) w3s[i] = W3[i];
  __syncthreads();
  int p = blockIdx.x*256 + tid;
  int cell = cellArr[p];
  float pf0 = x[p*3+1], pf1 = x[p*3+0], pf2 = x[p*3+2];
  float a[6] = {pf0, pf1, pf2, pf0 - cent[cell*3+0], pf1 - cent[cell*3+1], pf2 - cent[cell*3+2]};
  float h1[32];
  #pragma unroll
  for (int f = 0; f < 32; f++){
    float s = 0.f;
    #pragma unroll
    for (int i = 0; i < 6; i++) s += a[i]*w1s[i*32+f];
    h1[f] = fmaxf(s, 0.f);
  }
  float h2[64];
  #pragma unroll
  for (int f = 0; f < 64; f++){
    float s = 0.f;
    #pragma unroll
    for (int i = 0; i < 32; i++) s += h1[i]*w2s[i*64+f];
    h2[f] = fmaxf(s, 0.f);
  }
  for (int f = 0; f < 128; f++){
    float s = 0.f;
    #pragma unroll
    for (int i = 0; i < 64; i++) s += h2[i]*w3s[i*128+f];
    s = fmaxf(s, 0.f);
    A2[(size_t)p*256 + f] = (__bf16)s;
    atomicMax((int*)&pooled[cell*128 + f], __float_as_int(s));   // s >= 0: int-ordered max valid
  }
}

__global__ void k_gatherpool(const float* __restrict__ pooled, const int* __restrict__ cellArr,
                             __bf16* __restrict__ A2){
  int idx = blockIdx.x*256 + threadIdx.x;          // 65536*128
  int p = idx >> 7, f = idx & 127;
  A2[(size_t)p*256 + 128 + f] = (__bf16)pooled[cellArr[p]*128 + f];
}

__global__ void k_assemble(const float* __restrict__ pillar,
    const float* __restrict__ bn_g, const float* __restrict__ bn_b,
    const float* __restrict__ bn_mean, const float* __restrict__ bn_var,
    const float* __restrict__ cls_t, const float* __restrict__ pos,
    float* __restrict__ tokens){
  int idx = blockIdx.x*256 + threadIdx.x;          // 3232*768
  int m = idx / 768, d = idx % 768;
  int b = m / 101, t = m % 101;
  float v;
  if (t == 0) v = cls_t[d];
  else {
    int s = t - 1;
    float pv = pillar[((size_t)b*100 + s)*768 + d];
    float inv = bn_g[s]*rsqrtf(bn_var[s] + 1e-5f);
    v = (pv - bn_mean[s])*inv + bn_b[s];
  }
  tokens[idx] = v + pos[t*768 + d];
}

// ---------------- weight transpose-convert: W[K][N] f32 -> Wt[N][K] bf16 ----------------

__global__ __launch_bounds__(256) void k_transpose(const float* __restrict__ W, __bf16* __restrict__ Wt,
                                                   int K, int N){
  __shared__ float t[32][33];
  int n0 = blockIdx.x*32, k0 = blockIdx.y*32;
  int tx = threadIdx.x & 31, ty = threadIdx.x >> 5;   // ty 0..7
  #pragma unroll
  for (int i = 0; i < 32; i += 8){
    int k = k0 + ty + i, n = n0 + tx;
    t[ty+i][tx] = (k < K && n < N) ? W[(size_t)k*N + n] : 0.f;
  }
  __syncthreads();
  #pragma unroll
  for (int i = 0; i < 32; i += 8){
    int n = n0 + ty + i, k = k0 + tx;
    if (n < N && k < K) Wt[(size_t)n*K + k] = (__bf16)t[tx][ty+i];
  }
}

// ---------------- bf16 MFMA GEMM: C[M][N] = A[M][K] @ Bt[N][K]^T ----------------
// act: 0 none, 1 relu, 2 gelu(exact). Output: atomic-max into pillar via cellIdx,
// or bf16 outB, or fp32 outF (+res residual).

__global__ __launch_bounds__(256) void k_gemm(const __bf16* __restrict__ A, const __bf16* __restrict__ Bt,
    const float* __restrict__ bias, const float* __restrict__ res,
    float* __restrict__ outF, __bf16* __restrict__ outB,
    const int* __restrict__ cellIdx, float* __restrict__ pillar,
    int M, int N, int K, int act){
  __shared__ __bf16 As[128][40];   // +8 pad: 80B row stride, 16B aligned
  __shared__ __bf16 Bs[128][40];
  int tid  = threadIdx.x;
  int m0 = blockIdx.y*128, n0 = blockIdx.x*128;
  int wave = tid >> 6, lane = tid & 63;
  int wm = (wave >> 1)*64, wn = (wave & 1)*64;
  int r16 = lane & 15, q = lane >> 4;
  f4 acc[4][4];
  #pragma unroll
  for (int i = 0; i < 4; i++)
    #pragma unroll
    for (int j = 0; j < 4; j++) acc[i][j] = (f4){0.f,0.f,0.f,0.f};

  for (int kt = 0; kt < K; kt += 32){
    #pragma unroll
    for (int s = 0; s < 2; s++){
      int idx = tid + s*256;
      int row = idx >> 2, c8 = (idx & 3) << 3;   // 4 threads/row, 8 bf16 each
      int gm = m0 + row; if (gm > M-1) gm = M-1;
      *reinterpret_cast<uint4*>(&As[row][c8]) =
          *reinterpret_cast<const uint4*>(A + (size_t)gm*K + kt + c8);
      int gn = n0 + row; if (gn > N-1) gn = N-1;
      *reinterpret_cast<uint4*>(&Bs[row][c8]) =
          *reinterpret_cast<const uint4*>(Bt + (size_t)gn*K + kt + c8);
    }
    __syncthreads();
    bf8 af[4], bq[4];
    #pragma unroll
    for (int i = 0; i < 4; i++) af[i] = *reinterpret_cast<const bf8*>(&As[wm + i*16 + r16][q*8]);
    #pragma unroll
    for (int j = 0; j < 4; j++) bq[j] = *reinterpret_cast<const bf8*>(&Bs[wn + j*16 + r16][q*8]);
    #pragma unroll
    for (int i = 0; i < 4; i++)
      #pragma unroll
      for (int j = 0; j < 4; j++)
        acc[i][j] = __builtin_amdgcn_mfma_f32_16x16x32_bf16(af[i], bq[j], acc[i][j], 0, 0, 0);
    __syncthreads();
  }

  // epilogue: D row = q*4 + r, col = lane&15 (verified m89/m91 layout)
  #pragma unroll
  for (int i = 0; i < 4; i++){
    #pragma unroll
    for (int j = 0; j < 4; j++){
      int nn = n0 + wn + j*16 + r16;
      float bv = bias ? bias[nn] : 0.f;
      #pragma unroll
      for (int r = 0; r < 4; r++){
        int m = m0 + wm + i*16 + q*4 + r;
        if (m >= M) continue;
        float v = acc[i][j][r] + bv;
        if (act == 1) v = fmaxf(v, 0.f);
        else if (act == 2) v = 0.5f*v*(1.f + erff(v*0.70710678118654752f));
        if (cellIdx){
          atomicMax((int*)&pillar[(size_t)cellIdx[m]*N + nn], __float_as_int(v));
        } else if (outB){
          outB[(size_t)m*N + nn] = (__bf16)v;
        } else {
          float rv = res ? res[(size_t)m*N + nn] : 0.f;
          outF[(size_t)m*N + nn] = rv + v;
        }
      }
    }
  }
}

// ---------------- layernorm (row = 768) ----------------

__global__ __launch_bounds__(256) void k_ln(const float* __restrict__ in, const float* __restrict__ g,
    const float* __restrict__ bta, __bf16* __restrict__ outB, float* __restrict__ outF, int rowMul){
  int orow = blockIdx.x;
  const float* xr = in + (size_t)orow*rowMul*768;
  int tid = threadIdx.x;
  float v0 = xr[tid], v1 = xr[tid+256], v2 = xr[tid+512];
  float s = v0+v1+v2, s2 = v0*v0 + v1*v1 + v2*v2;
  #pragma unroll
  for (int off = 32; off > 0; off >>= 1){ s += __shfl_xor(s, off); s2 += __shfl_xor(s2, off); }
  __shared__ float rs[4], rq[4];
  int w = tid >> 6;
  if ((tid & 63) == 0){ rs[w] = s; rq[w] = s2; }
  __syncthreads();
  s = rs[0]+rs[1]+rs[2]+rs[3]; s2 = rq[0]+rq[1]+rq[2]+rq[3];
  float mean = s*(1.f/768.f);
  float var  = s2*(1.f/768.f) - mean*mean;
  float rstd = rsqrtf(var + 1e-5f);
  size_t ob = (size_t)orow*768;
  float y0 = (v0-mean)*rstd*g[tid]     + bta[tid];
  float y1 = (v1-mean)*rstd*g[tid+256] + bta[tid+256];
  float y2 = (v2-mean)*rstd*g[tid+512] + bta[tid+512];
  if (outB){ outB[ob+tid]=(__bf16)y0; outB[ob+tid+256]=(__bf16)y1; outB[ob+tid+512]=(__bf16)y2; }
  else     { outF[ob+tid]=y0;         outF[ob+tid+256]=y1;         outF[ob+tid+512]=y2; }
}

// ---------------- attention: one block per (b,h), T=101, HD=64 ----------------

__global__ __launch_bounds__(256) void k_attn(const float* __restrict__ qkv, __bf16* __restrict__ o){
  int b = blockIdx.x / 12, h = blockIdx.x % 12;
  __shared__ float Ks[101][65];
  __shared__ float Vs[101][65];
  int tid = threadIdx.x;
  for (int idx = tid; idx < 101*64; idx += 256){
    int t = idx >> 6, d = idx & 63;
    size_t base = ((size_t)(b*101 + t))*2304 + h*64 + d;
    Ks[t][d] = qkv[base + 768];
    Vs[t][d] = qkv[base + 1536];
  }
  __syncthreads();
  int wave = tid >> 6, lane = tid & 63;
  int j2 = lane + 64; int j2c = j2 > 100 ? 100 : j2;
  bool has2 = (j2 < 101);
  for (int i = wave; i < 101; i += 4){
    float qreg = qkv[((size_t)(b*101 + i))*2304 + h*64 + lane];
    float s1 = 0.f, s2 = 0.f;
    #pragma unroll
    for (int d = 0; d < 64; d++){
      float qd = __shfl(qreg, d);
      s1 += qd * Ks[lane][d];
      s2 += qd * Ks[j2c][d];
    }
    s1 *= 0.125f; s2 *= 0.125f;
    float mx = fmaxf(s1, has2 ? s2 : -1e30f);
    #pragma unroll
    for (int off = 32; off > 0; off >>= 1) mx = fmaxf(mx, __shfl_xor(mx, off));
    float p1 = expf(s1 - mx);
    float p2 = has2 ? expf(s2 - mx) : 0.f;
    float sum = p1 + p2;
    #pragma unroll
    for (int off = 32; off > 0; off >>= 1) sum += __shfl_xor(sum, off);
    float inv = 1.f / sum;
    float ov = 0.f;
    for (int j = 0; j < 101; j++){
      float pj = (j < 64) ? __shfl(p1, j) : __shfl(p2, j - 64);
      ov += pj * Vs[j][lane];
    }
    o[((size_t)(b*101 + i))*768 + h*64 + lane] = (__bf16)(ov * inv);
  }
}

__global__ void k_head(const float* __restrict__ cls, const float* __restrict__ hw,
                       const float* __restrict__ hb, float* __restrict__ out){
  int b = blockIdx.x, c = threadIdx.x;
  if (c < 40){
    float s = hb[c];
    for (int k = 0; k < 768; k++) s += cls[b*768 + k]*hw[k*40 + c];
    out[b*40 + c] = s;
  }
}

// ---------------- launch ----------------

extern "C" void kernel_launch(void* const* d_in, const int* in_sizes, int n_in,
                              void* d_out, int out_size, void* d_ws, size_t ws_size,
                              hipStream_t stream){
  const float* x       = (const float*)d_in[0];
  const float* W1      = (const float*)d_in[1];
  const float* W2      = (const float*)d_in[2];
  const float* W3      = (const float*)d_in[3];
  const float* Wa      = (const float*)d_in[4];
  const float* bn_g    = (const float*)d_in[5];
  const float* bn_b    = (const float*)d_in[6];
  const float* bn_mean = (const float*)d_in[7];
  const float* bn_var  = (const float*)d_in[8];
  const float* cls_t   = (const float*)d_in[9];
  const float* pos     = (const float*)d_in[10];
  const float* ln1_g   = (const float*)d_in[11];
  const float* ln1_b   = (const float*)d_in[12];
  const float* qkv_w   = (const float*)d_in[13];
  const float* proj_w  = (const float*)d_in[14];
  const float* proj_b  = (const float*)d_in[15];
  const float* ln2_g   = (const float*)d_in[16];
  const float* ln2_b   = (const float*)d_in[17];
  const float* fc1_w   = (const float*)d_in[18];
  const float* fc1_b   = (const float*)d_in[19];
  const float* fc2_w   = (const float*)d_in[20];
  const float* fc2_b   = (const float*)d_in[21];
  const float* norm_g  = (const float*)d_in[22];
  const float* norm_b  = (const float*)d_in[23];
  const float* head_w  = (const float*)d_in[24];
  const float* head_b  = (const float*)d_in[25];

  char* ws = (char*)d_ws;
  size_t off = 0;
  auto alloc = [&](size_t bytes)->void*{ void* p = ws + off; off += (bytes + 255) & ~(size_t)255; return p; };
  // zero-init region (contiguous): cnt, cent, pooled, pillar
  float* cnt     = (float*)alloc(3200*4);
  float* cent    = (float*)alloc(3200*3*4);
  float* pooled  = (float*)alloc((size_t)3200*128*4);
  float* pillar  = (float*)alloc((size_t)3200*768*4);
  size_t zbytes  = (size_t)((char*)pillar - (char*)cnt) + (size_t)3200*768*4;
  int*    cellArr= (int*)  alloc((size_t)65536*4);
  __bf16* A2     = (__bf16*)alloc((size_t)65536*256*2);
  float*  tokens = (float*)alloc((size_t)3232*768*4);
  __bf16* y      = (__bf16*)alloc((size_t)3232*768*2);
  float*  qkv    = (float*)alloc((size_t)3232*2304*4);
  __bf16* o      = (__bf16*)alloc((size_t)3232*768*2);
  __bf16* mlp    = (__bf16*)alloc((size_t)3232*3072*2);
  __bf16* wbuf   = (__bf16*)alloc((size_t)3072*768*2);
  float*  cls    = (float*)alloc((size_t)32*768*4);
  (void)ws_size; (void)in_sizes; (void)n_in; (void)out_size;

  hipMemsetAsync(cnt, 0, zbytes, stream);

  // pillar feature stage
  k_cell<<<256,256,0,stream>>>(x, cellArr, cnt, cent);
  k_centdiv<<<38,256,0,stream>>>(cent, cnt);
  k_pointmlp<<<256,256,0,stream>>>(x, W1, W2, W3, cent, cellArr, A2, pooled);
  k_gatherpool<<<32768,256,0,stream>>>(pooled, cellArr, A2);
  k_transpose<<<dim3(24,8),256,0,stream>>>(Wa, wbuf, 256, 768);
  // h2 = relu(A2 @ Wa); pillar = segment_max -> fused atomic epilogue
  k_gemm<<<dim3(6,512),256,0,stream>>>(A2, wbuf, nullptr, nullptr, nullptr, nullptr,
                                       cellArr, pillar, 65536, 768, 256, 1);
  k_assemble<<<9696,256,0,stream>>>(pillar, bn_g, bn_b, bn_mean, bn_var, cls_t, pos, tokens);

  // transformer
  for (int l = 0; l < 12; l++){
    k_ln<<<3232,256,0,stream>>>(tokens, ln1_g + l*768, ln1_b + l*768, y, nullptr, 1);
    k_transpose<<<dim3(72,24),256,0,stream>>>(qkv_w + (size_t)l*768*2304, wbuf, 768, 2304);
    k_gemm<<<dim3(18,26),256,0,stream>>>(y, wbuf, nullptr, nullptr, qkv, nullptr,
                                         nullptr, nullptr, 3232, 2304, 768, 0);
    k_attn<<<384,256,0,stream>>>(qkv, o);
    k_transpose<<<dim3(24,24),256,0,stream>>>(proj_w + (size_t)l*768*768, wbuf, 768, 768);
    k_gemm<<<dim3(6,26),256,0,stream>>>(o, wbuf, proj_b + l*768, tokens, tokens, nullptr,
                                        nullptr, nullptr, 3232, 768, 768, 0);
    k_ln<<<3232,256,0,stream>>>(tokens, ln2_g + l*768, ln2_b + l*768, y, nullptr, 1);
    k_transpose<<<dim3(96,24),256,0,stream>>>(fc1_w + (size_t)l*768*3072, wbuf, 768, 3072);
    k_gemm<<<dim3(24,26),256,0,stream>>>(y, wbuf, fc1_b + l*3072, nullptr, nullptr, mlp,
                                         nullptr, nullptr, 3232, 3072, 768, 2);
    k_transpose<<<dim3(24,96),256,0,stream>>>(fc2_w + (size_t)l*3072*768, wbuf, 3072, 768);
    k_gemm<<<dim3(6,26),256,0,stream>>>(mlp, wbuf, fc2_b + l*768, tokens, tokens, nullptr,
                                        nullptr, nullptr, 3232, 768, 3072, 0);
  }

  k_ln<<<32,256,0,stream>>>(tokens, norm_g, norm_b, nullptr, cls, 101);
  k_head<<<32,64,0,stream>>>(cls, head_w, head_b, (float*)d_out);
}

// Round 2
// 6095.021 us; speedup vs baseline: 1.0928x; 1.0928x over previous
//
#include <hip/hip_runtime.h>

typedef __bf16 bf8 __attribute__((ext_vector_type(8)));
typedef float  f4  __attribute__((ext_vector_type(4)));
typedef unsigned long long uptr;

__device__ __forceinline__ void gload16(const void* g, void* l){
  __builtin_amdgcn_global_load_lds(
      (const __attribute__((address_space(1))) unsigned int*)(uptr)g,
      (__attribute__((address_space(3))) unsigned int*)(uptr)l,
      16, 0, 0);
}

// ---------------- pillar stage ----------------

__global__ __launch_bounds__(256) void k_cell(const float* __restrict__ x, int* __restrict__ cellArr,
                                              float* __restrict__ cnt, float* __restrict__ cent){
  int p = blockIdx.x*256 + threadIdx.x;            // 65536 points
  float x0 = x[p*3+0], x1 = x[p*3+1], x2 = x[p*3+2];
  float y0 = fminf(fmaxf(x0 + 1.0f, 0.0f), 1.99f);
  float y1 = fminf(fmaxf(x2 + 1.0f, 0.0f), 1.99f);
  int i0 = (int)floorf(y0 / 0.2f);
  int i1 = (int)floorf(y1 / 0.2f);
  int b = p >> 11;
  int cell = b*100 + i0*10 + i1;
  cellArr[p] = cell;
  atomicAdd(&cnt[cell], 1.0f);
  atomicAdd(&cent[cell*3+0], x1);
  atomicAdd(&cent[cell*3+1], x0);
  atomicAdd(&cent[cell*3+2], x2);
}

__global__ void k_centdiv(float* cent, const float* cnt){
  int i = blockIdx.x*256 + threadIdx.x;
  if (i < 3200*3) cent[i] /= fmaxf(cnt[i/3], 1.0f);
}

// counting-sort scan: base = exclusive prefix of cnt; wptr = copy of base
__global__ __launch_bounds__(256) void k_scan(const float* __restrict__ cnt,
                                              int* __restrict__ base, int* __restrict__ wptr){
  __shared__ int a[256];
  int tid = threadIdx.x;
  int start = tid*13, end = start+13; if (end > 3200) end = 3200;
  int local = 0;
  for (int i = start; i < end; i++) local += (int)cnt[i];
  a[tid] = local;
  __syncthreads();
  for (int off = 1; off < 256; off <<= 1){
    int t = (tid >= off) ? a[tid - off] : 0;
    __syncthreads();
    a[tid] += t;
    __syncthreads();
  }
  int run = a[tid] - local;                    // exclusive prefix of this thread's chunk
  for (int i = start; i < end; i++){
    base[i] = run; wptr[i] = run;
    run += (int)cnt[i];
  }
}

__global__ __launch_bounds__(256) void k_scatter(const int* __restrict__ cellArr,
                                                 int* __restrict__ wptr, int* __restrict__ order){
  int p = blockIdx.x*256 + threadIdx.x;
  int c = cellArr[p];
  int pos = atomicAdd(&wptr[c], 1);
  order[pos] = p;
}

__global__ __launch_bounds__(256) void k_pointmlp(const float* __restrict__ x,
    const float* __restrict__ W1, const float* __restrict__ W2, const float* __restrict__ W3,
    const float* __restrict__ cent, const int* __restrict__ cellArr,
    const int* __restrict__ order, int* __restrict__ cellSlot, __bf16* __restrict__ A2){
  __shared__ float w1s[6*32];
  __shared__ float w2s[32*64];
  __shared__ float w3s[64*128];
  int tid = threadIdx.x;
  for (int i = tid; i < 192;  i += 256) w1s[i] = W1[i];
  for (int i = tid; i < 2048; i += 256) w2s[i] = W2[i];
  for (int i = tid; i < 8192; i += 256) w3s[i] = W3[i];
  __syncthreads();
  int s = blockIdx.x*256 + tid;                 // sorted slot
  int p = order[s];
  int cell = cellArr[p];
  cellSlot[s] = cell;
  float pf0 = x[p*3+1], pf1 = x[p*3+0], pf2 = x[p*3+2];
  float a[6] = {pf0, pf1, pf2, pf0 - cent[cell*3+0], pf1 - cent[cell*3+1], pf2 - cent[cell*3+2]};
  float h1[32];
  #pragma unroll
  for (int f = 0; f < 32; f++){
    float t = 0.f;
    #pragma unroll
    for (int i = 0; i < 6; i++) t += a[i]*w1s[i*32+f];
    h1[f] = fmaxf(t, 0.f);
  }
  float h2[64];
  #pragma unroll
  for (int f = 0; f < 64; f++){
    float t = 0.f;
    #pragma unroll
    for (int i = 0; i < 32; i++) t += h1[i]*w2s[i*64+f];
    h2[f] = fmaxf(t, 0.f);
  }
  for (int f0 = 0; f0 < 128; f0 += 8){
    __bf16 tmp[8];
    #pragma unroll
    for (int j = 0; j < 8; j++){
      float t = 0.f;
      #pragma unroll
      for (int i = 0; i < 64; i++) t += h2[i]*w3s[i*128+f0+j];
      tmp[j] = (__bf16)fmaxf(t, 0.f);
    }
    *reinterpret_cast<uint4*>(&A2[(size_t)s*256 + f0]) = *reinterpret_cast<uint4*>(tmp);
  }
}

// per-cell max over contiguous sorted rows of A2[:,0:128] -> pooled
__global__ __launch_bounds__(128) void k_poolh(const __bf16* __restrict__ A2,
    const int* __restrict__ base, const float* __restrict__ cnt, float* __restrict__ pooled){
  int c = blockIdx.x, f = threadIdx.x;
  int b0 = base[c], n = (int)cnt[c];
  float v = 0.f;
  for (int k = 0; k < n; k++) v = fmaxf(v, (float)A2[(size_t)(b0+k)*256 + f]);
  pooled[c*128 + f] = v;
}

__global__ __launch_bounds__(256) void k_fill(const float* __restrict__ pooled,
    const int* __restrict__ cellSlot, __bf16* __restrict__ A2){
  int idx = blockIdx.x*256 + threadIdx.x;       // 65536*128
  int s = idx >> 7, f = idx & 127;
  A2[(size_t)s*256 + 128 + f] = (__bf16)pooled[cellSlot[s]*128 + f];
}

// per-cell max over h2 chunk rows -> pillar (pillar pre-zeroed; values >= 0)
__global__ __launch_bounds__(256) void k_pillarpool(const __bf16* __restrict__ h2c,
    const int* __restrict__ base, const float* __restrict__ cnt, float* __restrict__ pillar, int cs){
  int c = blockIdx.x, tid = threadIdx.x;
  int b0 = base[c], e0 = b0 + (int)cnt[c];
  int lo = b0 > cs ? b0 : cs;
  int hi = e0 < cs + 16384 ? e0 : cs + 16384;
  if (lo >= hi) return;
  for (int f = tid; f < 768; f += 256){
    float v = 0.f;
    for (int s = lo; s < hi; s++) v = fmaxf(v, (float)h2c[(size_t)(s - cs)*768 + f]);
    atomicMax((int*)&pillar[(size_t)c*768 + f], __float_as_int(v));
  }
}

__global__ void k_assemble(const float* __restrict__ pillar,
    const float* __restrict__ bn_g, const float* __restrict__ bn_b,
    const float* __restrict__ bn_mean, const float* __restrict__ bn_var,
    const float* __restrict__ cls_t, const float* __restrict__ pos,
    float* __restrict__ tokens){
  int idx = blockIdx.x*256 + threadIdx.x;          // 3232*768
  int m = idx / 768, d = idx % 768;
  int b = m / 101, t = m % 101;
  float v;
  if (t == 0) v = cls_t[d];
  else {
    int s = t - 1;
    float pv = pillar[((size_t)b*100 + s)*768 + d];
    float inv = bn_g[s]*rsqrtf(bn_var[s] + 1e-5f);
    v = (pv - bn_mean[s])*inv + bn_b[s];
  }
  tokens[idx] = v + pos[t*768 + d];
}

// ---------------- weight transpose-convert ----------------

__global__ __launch_bounds__(256) void k_transpose(const float* __restrict__ W, __bf16* __restrict__ Wt,
                                                   int K, int N){
  __shared__ float t[32][33];
  int n0 = blockIdx.x*32, k0 = blockIdx.y*32;
  int tx = threadIdx.x & 31, ty = threadIdx.x >> 5;
  #pragma unroll
  for (int i = 0; i < 32; i += 8){
    int k = k0 + ty + i, n = n0 + tx;
    t[ty+i][tx] = (k < K && n < N) ? W[(size_t)k*N + n] : 0.f;
  }
  __syncthreads();
  #pragma unroll
  for (int i = 0; i < 32; i += 8){
    int n = n0 + ty + i, k = k0 + tx;
    if (n < N && k < K) Wt[(size_t)n*K + k] = (__bf16)t[tx][ty+i];
  }
}

// all 4 per-layer weights in one launch (dims all multiples of 32, no guards)
__global__ __launch_bounds__(256) void k_transpose_all(
    const float* __restrict__ qw, const float* __restrict__ pw,
    const float* __restrict__ f1, const float* __restrict__ f2,
    __bf16* __restrict__ wq, __bf16* __restrict__ wp,
    __bf16* __restrict__ w1, __bf16* __restrict__ w2){
  int id = blockIdx.x;
  const float* W; __bf16* Wt; int K, N, nx, ny;
  if (id < 1728){ W=qw; Wt=wq; K=768;  N=2304; nx=id%72; ny=id/72; }
  else if (id < 2304){ id-=1728; W=pw; Wt=wp; K=768;  N=768;  nx=id%24; ny=id/24; }
  else if (id < 4608){ id-=2304; W=f1; Wt=w1; K=768;  N=3072; nx=id%96; ny=id/96; }
  else {               id-=4608; W=f2; Wt=w2; K=3072; N=768;  nx=id%24; ny=id/24; }
  __shared__ float t[32][33];
  int n0 = nx*32, k0 = ny*32;
  int tx = threadIdx.x & 31, ty = threadIdx.x >> 5;
  #pragma unroll
  for (int i = 0; i < 32; i += 8) t[ty+i][tx] = W[(size_t)(k0+ty+i)*N + n0+tx];
  __syncthreads();
  #pragma unroll
  for (int i = 0; i < 32; i += 8) Wt[(size_t)(n0+ty+i)*K + k0+tx] = (__bf16)t[tx][ty+i];
}

// ---------------- bf16 MFMA GEMM (m97-style global_load_lds staging) ----------------
// C[M][N] = A[M][K] @ Bt[N][K]^T ; act: 0 none, 1 relu, 2 gelu(exact)

__global__ __launch_bounds__(256) void k_gemm(const __bf16* __restrict__ A, const __bf16* __restrict__ Bt,
    const float* __restrict__ bias, const float* __restrict__ res,
    float* __restrict__ outF, __bf16* __restrict__ outB,
    int M, int N, int K, int act){
  __shared__ alignas(16) __bf16 As[128*32];   // unpadded: fragment reads are contiguous 1KB/wave
  __shared__ alignas(16) __bf16 Bs[128*32];
  int tid  = threadIdx.x;
  int m0 = blockIdx.y*128, n0 = blockIdx.x*128;
  int wave = tid >> 6, lane = tid & 63;
  int wm = (wave >> 1)*64, wn = (wave & 1)*64;
  int r16 = lane & 15, q = lane >> 4;
  int lrow = lane >> 2, lpc = lane & 3;       // staging: 4 lanes/row, 16B chunks
  f4 acc[4][4];
  #pragma unroll
  for (int i = 0; i < 4; i++)
    #pragma unroll
    for (int j = 0; j < 4; j++) acc[i][j] = (f4){0.f,0.f,0.f,0.f};

  for (int kt = 0; kt < K; kt += 32){
    #pragma unroll
    for (int s = 0; s < 2; s++){
      int rg  = wave*2 + s;                   // 0..7: 16-row (1KB) region
      int row = rg*16 + lrow;
      int gm = m0 + row; if (gm >= M) gm = M - 1;
      gload16(A  + (size_t)gm*K + kt + lpc*8, (char*)As + rg*1024 + lane*16);
      int gn = n0 + row;                      // N always multiple of 128
      gload16(Bt + (size_t)gn*K + kt + lpc*8, (char*)Bs + rg*1024 + lane*16);
    }
    __syncthreads();
    bf8 af[4], bq[4];
    #pragma unroll
    for (int i = 0; i < 4; i++) af[i] = *reinterpret_cast<const bf8*>(&As[(wm + i*16 + r16)*32 + q*8]);
    #pragma unroll
    for (int j = 0; j < 4; j++) bq[j] = *reinterpret_cast<const bf8*>(&Bs[(wn + j*16 + r16)*32 + q*8]);
    #pragma unroll
    for (int i = 0; i < 4; i++)
      #pragma unroll
      for (int j = 0; j < 4; j++)
        acc[i][j] = __builtin_amdgcn_mfma_f32_16x16x32_bf16(af[i], bq[j], acc[i][j], 0, 0, 0);
    __syncthreads();
  }

  #pragma unroll
  for (int i = 0; i < 4; i++){
    #pragma unroll
    for (int j = 0; j < 4; j++){
      int nn = n0 + wn + j*16 + r16;
      float bv = bias ? bias[nn] : 0.f;
      #pragma unroll
      for (int r = 0; r < 4; r++){
        int m = m0 + wm + i*16 + q*4 + r;
        if (m >= M) continue;
        float v = acc[i][j][r] + bv;
        if (act == 1) v = fmaxf(v, 0.f);
        else if (act == 2) v = 0.5f*v*(1.f + erff(v*0.70710678118654752f));
        if (outB){
          outB[(size_t)m*N + nn] = (__bf16)v;
        } else {
          float rv = res ? res[(size_t)m*N + nn] : 0.f;
          outF[(size_t)m*N + nn] = rv + v;
        }
      }
    }
  }
}

// ---------------- layernorm (row = 768) ----------------

__global__ __launch_bounds__(256) void k_ln(const float* __restrict__ in, const float* __restrict__ g,
    const float* __restrict__ bta, __bf16* __restrict__ outB, float* __restrict__ outF, int rowMul){
  int orow = blockIdx.x;
  const float* xr = in + (size_t)orow*rowMul*768;
  int tid = threadIdx.x;
  float v0 = xr[tid], v1 = xr[tid+256], v2 = xr[tid+512];
  float s = v0+v1+v2, s2 = v0*v0 + v1*v1 + v2*v2;
  #pragma unroll
  for (int off = 32; off > 0; off >>= 1){ s += __shfl_xor(s, off); s2 += __shfl_xor(s2, off); }
  __shared__ float rs[4], rq[4];
  int w = tid >> 6;
  if ((tid & 63) == 0){ rs[w] = s; rq[w] = s2; }
  __syncthreads();
  s = rs[0]+rs[1]+rs[2]+rs[3]; s2 = rq[0]+rq[1]+rq[2]+rq[3];
  float mean = s*(1.f/768.f);
  float var  = s2*(1.f/768.f) - mean*mean;
  float rstd = rsqrtf(var + 1e-5f);
  size_t ob = (size_t)orow*768;
  float y0 = (v0-mean)*rstd*g[tid]     + bta[tid];
  float y1 = (v1-mean)*rstd*g[tid+256] + bta[tid+256];
  float y2 = (v2-mean)*rstd*g[tid+512] + bta[tid+512];
  if (outB){ outB[ob+tid]=(__bf16)y0; outB[ob+tid+256]=(__bf16)y1; outB[ob+tid+512]=(__bf16)y2; }
  else     { outF[ob+tid]=y0;         outF[ob+tid+256]=y1;         outF[ob+tid+512]=y2; }
}

// ---------------- attention: one block per (b,h), T=101, HD=64 ----------------

__global__ __launch_bounds__(256) void k_attn(const float* __restrict__ qkv, __bf16* __restrict__ o){
  int b = blockIdx.x / 12, h = blockIdx.x % 12;
  __shared__ float Ks[101][65];
  __shared__ float Vs[101][65];
  int tid = threadIdx.x;
  for (int idx = tid; idx < 101*64; idx += 256){
    int t = idx >> 6, d = idx & 63;
    size_t base = ((size_t)(b*101 + t))*2304 + h*64 + d;
    Ks[t][d] = qkv[base + 768];
    Vs[t][d] = qkv[base + 1536];
  }
  __syncthreads();
  int wave = tid >> 6, lane = tid & 63;
  int j2 = lane + 64; int j2c = j2 > 100 ? 100 : j2;
  bool has2 = (j2 < 101);
  for (int i = wave; i < 101; i += 4){
    float qreg = qkv[((size_t)(b*101 + i))*2304 + h*64 + lane];
    float s1 = 0.f, s2 = 0.f;
    #pragma unroll
    for (int d = 0; d < 64; d++){
      float qd = __shfl(qreg, d);
      s1 += qd * Ks[lane][d];
      s2 += qd * Ks[j2c][d];
    }
    s1 *= 0.125f; s2 *= 0.125f;
    float mx = fmaxf(s1, has2 ? s2 : -1e30f);
    #pragma unroll
    for (int off = 32; off > 0; off >>= 1) mx = fmaxf(mx, __shfl_xor(mx, off));
    float p1 = expf(s1 - mx);
    float p2 = has2 ? expf(s2 - mx) : 0.f;
    float sum = p1 + p2;
    #pragma unroll
    for (int off = 32; off > 0; off >>= 1) sum += __shfl_xor(sum, off);
    float inv = 1.f / sum;
    float ov = 0.f;
    for (int j = 0; j < 101; j++){
      float pj = (j < 64) ? __shfl(p1, j) : __shfl(p2, j - 64);
      ov += pj * Vs[j][lane];
    }
    o[((size_t)(b*101 + i))*768 + h*64 + lane] = (__bf16)(ov * inv);
  }
}

__global__ void k_head(const float* __restrict__ cls, const float* __restrict__ hw,
                       const float* __restrict__ hb, float* __restrict__ out){
  int b = blockIdx.x, c = threadIdx.x;
  if (c < 40){
    float s = hb[c];
    for (int k = 0; k < 768; k++) s += cls[b*768 + k]*hw[k*40 + c];
    out[b*40 + c] = s;
  }
}

// ---------------- launch ----------------

extern "C" void kernel_launch(void* const* d_in, const int* in_sizes, int n_in,
                              void* d_out, int out_size, void* d_ws, size_t ws_size,
                              hipStream_t stream){
  const float* x       = (const float*)d_in[0];
  const float* W1      = (const float*)d_in[1];
  const float* W2      = (const float*)d_in[2];
  const float* W3      = (const float*)d_in[3];
  const float* Wa      = (const float*)d_in[4];
  const float* bn_g    = (const float*)d_in[5];
  const float* bn_b    = (const float*)d_in[6];
  const float* bn_mean = (const float*)d_in[7];
  const float* bn_var  = (const float*)d_in[8];
  const float* cls_t   = (const float*)d_in[9];
  const float* pos     = (const float*)d_in[10];
  const float* ln1_g   = (const float*)d_in[11];
  const float* ln1_b   = (const float*)d_in[12];
  const float* qkv_w   = (const float*)d_in[13];
  const float* proj_w  = (const float*)d_in[14];
  const float* proj_b  = (const float*)d_in[15];
  const float* ln2_g   = (const float*)d_in[16];
  const float* ln2_b   = (const float*)d_in[17];
  const float* fc1_w   = (const float*)d_in[18];
  const float* fc1_b   = (const float*)d_in[19];
  const float* fc2_w   = (const float*)d_in[20];
  const float* fc2_b   = (const float*)d_in[21];
  const float* norm_g  = (const float*)d_in[22];
  const float* norm_b  = (const float*)d_in[23];
  const float* head_w  = (const float*)d_in[24];
  const float* head_b  = (const float*)d_in[25];

  char* ws = (char*)d_ws;
  size_t off = 0;
  auto alloc = [&](size_t bytes)->void*{ void* p = ws + off; off += (bytes + 255) & ~(size_t)255; return p; };
  // --- persistent region ---
  float* cnt     = (float*)alloc(3200*4);
  float* cent    = (float*)alloc(3200*3*4);
  float* pillar  = (float*)alloc((size_t)3200*768*4);
  size_t zbytes  = (size_t)((char*)pillar - (char*)cnt) + (size_t)3200*768*4;
  int*   base    = (int*)  alloc(3200*4);
  int*   wptr    = (int*)  alloc(3200*4);
  int*   order   = (int*)  alloc((size_t)65536*4);
  int*   cellSlot= (int*)  alloc((size_t)65536*4);
  int*   cellArr = (int*)  alloc((size_t)65536*4);
  float* pooled  = (float*)alloc((size_t)3200*128*4);
  float* tokens  = (float*)alloc((size_t)3232*768*4);
  float* cls     = (float*)alloc((size_t)32*768*4);
  __bf16* wWa    = (__bf16*)alloc((size_t)768*256*2);
  // --- overlaid region R ---
  size_t offR = off;
  // pillar phase
  __bf16* A2  = (__bf16*)alloc((size_t)65536*256*2);
  __bf16* h2c = (__bf16*)alloc((size_t)16384*768*2);
  size_t endPillarPhase = off;
  // transformer phase (overlays A2/h2c)
  off = offR;
  __bf16* y    = (__bf16*)alloc((size_t)3232*768*2);
  float*  qkv  = (float*) alloc((size_t)3232*2304*4);
  __bf16* o    = (__bf16*)alloc((size_t)3232*768*2);
  __bf16* mlp  = (__bf16*)alloc((size_t)3232*3072*2);
  __bf16* wq   = (__bf16*)alloc((size_t)768*2304*2);
  __bf16* wp   = (__bf16*)alloc((size_t)768*768*2);
  __bf16* w1   = (__bf16*)alloc((size_t)768*3072*2);
  __bf16* w2   = (__bf16*)alloc((size_t)3072*768*2);
  if (off < endPillarPhase) off = endPillarPhase;
  (void)ws_size; (void)in_sizes; (void)n_in; (void)out_size;

  hipMemsetAsync(cnt, 0, zbytes, stream);

  // pillar feature stage (counting-sorted by cell -> dense segment ops, no hot atomics)
  k_cell<<<256,256,0,stream>>>(x, cellArr, cnt, cent);
  k_centdiv<<<38,256,0,stream>>>(cent, cnt);
  k_scan<<<1,256,0,stream>>>(cnt, base, wptr);
  k_scatter<<<256,256,0,stream>>>(cellArr, wptr, order);
  k_pointmlp<<<256,256,0,stream>>>(x, W1, W2, W3, cent, cellArr, order, cellSlot, A2);
  k_poolh<<<3200,128,0,stream>>>(A2, base, cnt, pooled);
  k_fill<<<32768,256,0,stream>>>(pooled, cellSlot, A2);
  k_transpose<<<dim3(24,8),256,0,stream>>>(Wa, wWa, 256, 768);
  for (int c = 0; c < 4; c++){
    k_gemm<<<dim3(6,128),256,0,stream>>>(A2 + (size_t)c*16384*256, wWa, nullptr, nullptr,
                                         nullptr, h2c, 16384, 768, 256, 1);
    k_pillarpool<<<3200,256,0,stream>>>(h2c, base, cnt, pillar, c*16384);
  }
  k_assemble<<<9696,256,0,stream>>>(pillar, bn_g, bn_b, bn_mean, bn_var, cls_t, pos, tokens);

  // transformer
  for (int l = 0; l < 12; l++){
    k_transpose_all<<<6912,256,0,stream>>>(qkv_w + (size_t)l*768*2304, proj_w + (size_t)l*768*768,
                                           fc1_w + (size_t)l*768*3072, fc2_w + (size_t)l*3072*768,
                                           wq, wp, w1, w2);
    k_ln<<<3232,256,0,stream>>>(tokens, ln1_g + l*768, ln1_b + l*768, y, nullptr, 1);
    k_gemm<<<dim3(18,26),256,0,stream>>>(y, wq, nullptr, nullptr, qkv, nullptr, 3232, 2304, 768, 0);
    k_attn<<<384,256,0,stream>>>(qkv, o);
    k_gemm<<<dim3(6,26),256,0,stream>>>(o, wp, proj_b + l*768, tokens, tokens, nullptr, 3232, 768, 768, 0);
    k_ln<<<3232,256,0,stream>>>(tokens, ln2_g + l*768, ln2_b + l*768, y, nullptr, 1);
    k_gemm<<<dim3(24,26),256,0,stream>>>(y, w1, fc1_b + l*3072, nullptr, nullptr, mlp, 3232, 3072, 768, 2);
    k_gemm<<<dim3(6,26),256,0,stream>>>(mlp, w2, fc2_b + l*768, tokens, tokens, nullptr, 3232, 768, 3072, 0);
  }

  k_ln<<<32,256,0,stream>>>(tokens, norm_g, norm_b, nullptr, cls, 101);
  k_head<<<32,64,0,stream>>>(cls, head_w, head_b, (float*)d_out);
}

// Round 3
// 4253.198 us; speedup vs baseline: 1.5661x; 1.4330x over previous
//
#include <hip/hip_runtime.h>

typedef __bf16 bf8 __attribute__((ext_vector_type(8)));
typedef float  f4  __attribute__((ext_vector_type(4)));
typedef unsigned long long uptr;

__device__ __forceinline__ void gload16(const void* g, void* l){
  __builtin_amdgcn_global_load_lds(
      (const __attribute__((address_space(1))) unsigned int*)(uptr)g,
      (__attribute__((address_space(3))) unsigned int*)(uptr)l,
      16, 0, 0);
}

// ---------------- pillar stage ----------------

__global__ __launch_bounds__(256) void k_cell(const float* __restrict__ x, int* __restrict__ cellArr,
                                              float* __restrict__ cnt, float* __restrict__ cent){
  int p = blockIdx.x*256 + threadIdx.x;            // 65536 points
  float x0 = x[p*3+0], x1 = x[p*3+1], x2 = x[p*3+2];
  float y0 = fminf(fmaxf(x0 + 1.0f, 0.0f), 1.99f);
  float y1 = fminf(fmaxf(x2 + 1.0f, 0.0f), 1.99f);
  int i0 = (int)floorf(y0 / 0.2f);
  int i1 = (int)floorf(y1 / 0.2f);
  int b = p >> 11;
  int cell = b*100 + i0*10 + i1;
  cellArr[p] = cell;
  atomicAdd(&cnt[cell], 1.0f);
  atomicAdd(&cent[cell*3+0], x1);
  atomicAdd(&cent[cell*3+1], x0);
  atomicAdd(&cent[cell*3+2], x2);
}

__global__ void k_centdiv(float* cent, const float* cnt){
  int i = blockIdx.x*256 + threadIdx.x;
  if (i < 3200*3) cent[i] /= fmaxf(cnt[i/3], 1.0f);
}

// counting-sort scan: base = exclusive prefix of cnt; wptr = copy of base
__global__ __launch_bounds__(256) void k_scan(const float* __restrict__ cnt,
                                              int* __restrict__ base, int* __restrict__ wptr){
  __shared__ int a[256];
  int tid = threadIdx.x;
  int start = tid*13, end = start+13; if (end > 3200) end = 3200;
  int local = 0;
  for (int i = start; i < end; i++) local += (int)cnt[i];
  a[tid] = local;
  __syncthreads();
  for (int off = 1; off < 256; off <<= 1){
    int t = (tid >= off) ? a[tid - off] : 0;
    __syncthreads();
    a[tid] += t;
    __syncthreads();
  }
  int run = a[tid] - local;
  for (int i = start; i < end; i++){
    base[i] = run; wptr[i] = run;
    run += (int)cnt[i];
  }
}

__global__ __launch_bounds__(256) void k_scatter(const int* __restrict__ cellArr,
                                                 int* __restrict__ wptr, int* __restrict__ order){
  int p = blockIdx.x*256 + threadIdx.x;
  int c = cellArr[p];
  int pos = atomicAdd(&wptr[c], 1);
  order[pos] = p;
}

__global__ __launch_bounds__(256) void k_pointmlp(const float* __restrict__ x,
    const float* __restrict__ W1, const float* __restrict__ W2, const float* __restrict__ W3,
    const float* __restrict__ cent, const int* __restrict__ cellArr,
    const int* __restrict__ order, int* __restrict__ cellSlot, __bf16* __restrict__ A2){
  __shared__ float w1s[6*32];
  __shared__ float w2s[32*64];
  __shared__ float w3s[64*128];
  int tid = threadIdx.x;
  for (int i = tid; i < 192;  i += 256) w1s[i] = W1[i];
  for (int i = tid; i < 2048; i += 256) w2s[i] = W2[i];
  for (int i = tid; i < 8192; i += 256) w3s[i] = W3[i];
  __syncthreads();
  int s = blockIdx.x*256 + tid;                 // sorted slot
  int p = order[s];
  int cell = cellArr[p];
  cellSlot[s] = cell;
  float pf0 = x[p*3+1], pf1 = x[p*3+0], pf2 = x[p*3+2];
  float a[6] = {pf0, pf1, pf2, pf0 - cent[cell*3+0], pf1 - cent[cell*3+1], pf2 - cent[cell*3+2]};
  float h1[32];
  #pragma unroll
  for (int f = 0; f < 32; f++){
    float t = 0.f;
    #pragma unroll
    for (int i = 0; i < 6; i++) t += a[i]*w1s[i*32+f];
    h1[f] = fmaxf(t, 0.f);
  }
  float h2[64];
  #pragma unroll
  for (int f = 0; f < 64; f++){
    float t = 0.f;
    #pragma unroll
    for (int i = 0; i < 32; i++) t += h1[i]*w2s[i*64+f];
    h2[f] = fmaxf(t, 0.f);
  }
  for (int f0 = 0; f0 < 128; f0 += 8){
    __bf16 tmp[8];
    #pragma unroll
    for (int j = 0; j < 8; j++){
      float t = 0.f;
      #pragma unroll
      for (int i = 0; i < 64; i++) t += h2[i]*w3s[i*128+f0+j];
      tmp[j] = (__bf16)fmaxf(t, 0.f);
    }
    *reinterpret_cast<uint4*>(&A2[(size_t)s*256 + f0]) = *reinterpret_cast<uint4*>(tmp);
  }
}

__global__ __launch_bounds__(128) void k_poolh(const __bf16* __restrict__ A2,
    const int* __restrict__ base, const float* __restrict__ cnt, float* __restrict__ pooled){
  int c = blockIdx.x, f = threadIdx.x;
  int b0 = base[c], n = (int)cnt[c];
  float v = 0.f;
  for (int k = 0; k < n; k++) v = fmaxf(v, (float)A2[(size_t)(b0+k)*256 + f]);
  pooled[c*128 + f] = v;
}

__global__ __launch_bounds__(256) void k_fill(const float* __restrict__ pooled,
    const int* __restrict__ cellSlot, __bf16* __restrict__ A2){
  int idx = blockIdx.x*256 + threadIdx.x;       // 65536*128
  int s = idx >> 7, f = idx & 127;
  A2[(size_t)s*256 + 128 + f] = (__bf16)pooled[cellSlot[s]*128 + f];
}

__global__ __launch_bounds__(256) void k_pillarpool(const __bf16* __restrict__ h2c,
    const int* __restrict__ base, const float* __restrict__ cnt, float* __restrict__ pillar, int cs){
  int c = blockIdx.x, tid = threadIdx.x;
  int b0 = base[c], e0 = b0 + (int)cnt[c];
  int lo = b0 > cs ? b0 : cs;
  int hi = e0 < cs + 16384 ? e0 : cs + 16384;
  if (lo >= hi) return;
  for (int f = tid; f < 768; f += 256){
    float v = 0.f;
    for (int s = lo; s < hi; s++) v = fmaxf(v, (float)h2c[(size_t)(s - cs)*768 + f]);
    atomicMax((int*)&pillar[(size_t)c*768 + f], __float_as_int(v));
  }
}

__global__ void k_assemble(const float* __restrict__ pillar,
    const float* __restrict__ bn_g, const float* __restrict__ bn_b,
    const float* __restrict__ bn_mean, const float* __restrict__ bn_var,
    const float* __restrict__ cls_t, const float* __restrict__ pos,
    float* __restrict__ tokens){
  int idx = blockIdx.x*256 + threadIdx.x;          // 3232*768
  int m = idx / 768, d = idx % 768;
  int b = m / 101, t = m % 101;
  float v;
  if (t == 0) v = cls_t[d];
  else {
    int s = t - 1;
    float pv = pillar[((size_t)b*100 + s)*768 + d];
    float inv = bn_g[s]*rsqrtf(bn_var[s] + 1e-5f);
    v = (pv - bn_mean[s])*inv + bn_b[s];
  }
  tokens[idx] = v + pos[t*768 + d];
}

// ---------------- weight transpose-convert ----------------

__global__ __launch_bounds__(256) void k_transpose(const float* __restrict__ W, __bf16* __restrict__ Wt,
                                                   int K, int N){
  __shared__ float t[32][33];
  int n0 = blockIdx.x*32, k0 = blockIdx.y*32;
  int tx = threadIdx.x & 31, ty = threadIdx.x >> 5;
  #pragma unroll
  for (int i = 0; i < 32; i += 8){
    int k = k0 + ty + i, n = n0 + tx;
    t[ty+i][tx] = (k < K && n < N) ? W[(size_t)k*N + n] : 0.f;
  }
  __syncthreads();
  #pragma unroll
  for (int i = 0; i < 32; i += 8){
    int n = n0 + ty + i, k = k0 + tx;
    if (n < N && k < K) Wt[(size_t)n*K + k] = (__bf16)t[tx][ty+i];
  }
}

__global__ __launch_bounds__(256) void k_transpose_all(
    const float* __restrict__ qw, const float* __restrict__ pw,
    const float* __restrict__ f1, const float* __restrict__ f2,
    __bf16* __restrict__ wq, __bf16* __restrict__ wp,
    __bf16* __restrict__ w1, __bf16* __restrict__ w2){
  int id = blockIdx.x;
  const float* W; __bf16* Wt; int K, N, nx, ny;
  if (id < 1728){ W=qw; Wt=wq; K=768;  N=2304; nx=id%72; ny=id/72; }
  else if (id < 2304){ id-=1728; W=pw; Wt=wp; K=768;  N=768;  nx=id%24; ny=id/24; }
  else if (id < 4608){ id-=2304; W=f1; Wt=w1; K=768;  N=3072; nx=id%96; ny=id/96; }
  else {               id-=4608; W=f2; Wt=w2; K=3072; N=768;  nx=id%24; ny=id/24; }
  __shared__ float t[32][33];
  int n0 = nx*32, k0 = ny*32;
  int tx = threadIdx.x & 31, ty = threadIdx.x >> 5;
  #pragma unroll
  for (int i = 0; i < 32; i += 8) t[ty+i][tx] = W[(size_t)(k0+ty+i)*N + n0+tx];
  __syncthreads();
  #pragma unroll
  for (int i = 0; i < 32; i += 8) Wt[(size_t)(n0+ty+i)*K + k0+tx] = (__bf16)t[tx][ty+i];
}

// ---------------- bf16 MFMA GEMM (m97-style global_load_lds staging) ----------------

__global__ __launch_bounds__(256) void k_gemm(const __bf16* __restrict__ A, const __bf16* __restrict__ Bt,
    const float* __restrict__ bias, const float* __restrict__ res,
    float* __restrict__ outF, __bf16* __restrict__ outB,
    int M, int N, int K, int act){
  __shared__ alignas(16) __bf16 As[128*32];
  __shared__ alignas(16) __bf16 Bs[128*32];
  int tid  = threadIdx.x;
  int m0 = blockIdx.y*128, n0 = blockIdx.x*128;
  int wave = tid >> 6, lane = tid & 63;
  int wm = (wave >> 1)*64, wn = (wave & 1)*64;
  int r16 = lane & 15, q = lane >> 4;
  int lrow = lane >> 2, lpc = lane & 3;
  f4 acc[4][4];
  #pragma unroll
  for (int i = 0; i < 4; i++)
    #pragma unroll
    for (int j = 0; j < 4; j++) acc[i][j] = (f4){0.f,0.f,0.f,0.f};

  for (int kt = 0; kt < K; kt += 32){
    #pragma unroll
    for (int s = 0; s < 2; s++){
      int rg  = wave*2 + s;
      int row = rg*16 + lrow;
      int gm = m0 + row; if (gm >= M) gm = M - 1;
      gload16(A  + (size_t)gm*K + kt + lpc*8, (char*)As + rg*1024 + lane*16);
      int gn = n0 + row;
      gload16(Bt + (size_t)gn*K + kt + lpc*8, (char*)Bs + rg*1024 + lane*16);
    }
    __syncthreads();
    bf8 af[4], bq[4];
    #pragma unroll
    for (int i = 0; i < 4; i++) af[i] = *reinterpret_cast<const bf8*>(&As[(wm + i*16 + r16)*32 + q*8]);
    #pragma unroll
    for (int j = 0; j < 4; j++) bq[j] = *reinterpret_cast<const bf8*>(&Bs[(wn + j*16 + r16)*32 + q*8]);
    #pragma unroll
    for (int i = 0; i < 4; i++)
      #pragma unroll
      for (int j = 0; j < 4; j++)
        acc[i][j] = __builtin_amdgcn_mfma_f32_16x16x32_bf16(af[i], bq[j], acc[i][j], 0, 0, 0);
    __syncthreads();
  }

  #pragma unroll
  for (int i = 0; i < 4; i++){
    #pragma unroll
    for (int j = 0; j < 4; j++){
      int nn = n0 + wn + j*16 + r16;
      float bv = bias ? bias[nn] : 0.f;
      #pragma unroll
      for (int r = 0; r < 4; r++){
        int m = m0 + wm + i*16 + q*4 + r;
        if (m >= M) continue;
        float v = acc[i][j][r] + bv;
        if (act == 1) v = fmaxf(v, 0.f);
        else if (act == 2) v = 0.5f*v*(1.f + erff(v*0.70710678118654752f));
        if (outB){
          outB[(size_t)m*N + nn] = (__bf16)v;
        } else {
          float rv = res ? res[(size_t)m*N + nn] : 0.f;
          outF[(size_t)m*N + nn] = rv + v;
        }
      }
    }
  }
}

// ---------------- layernorm (row = 768) ----------------

__global__ __launch_bounds__(256) void k_ln(const float* __restrict__ in, const float* __restrict__ g,
    const float* __restrict__ bta, __bf16* __restrict__ outB, float* __restrict__ outF, int rowMul){
  int orow = blockIdx.x;
  const float* xr = in + (size_t)orow*rowMul*768;
  int tid = threadIdx.x;
  float v0 = xr[tid], v1 = xr[tid+256], v2 = xr[tid+512];
  float s = v0+v1+v2, s2 = v0*v0 + v1*v1 + v2*v2;
  #pragma unroll
  for (int off = 32; off > 0; off >>= 1){ s += __shfl_xor(s, off); s2 += __shfl_xor(s2, off); }
  __shared__ float rs[4], rq[4];
  int w = tid >> 6;
  if ((tid & 63) == 0){ rs[w] = s; rq[w] = s2; }
  __syncthreads();
  s = rs[0]+rs[1]+rs[2]+rs[3]; s2 = rq[0]+rq[1]+rq[2]+rq[3];
  float mean = s*(1.f/768.f);
  float var  = s2*(1.f/768.f) - mean*mean;
  float rstd = rsqrtf(var + 1e-5f);
  size_t ob = (size_t)orow*768;
  float y0 = (v0-mean)*rstd*g[tid]     + bta[tid];
  float y1 = (v1-mean)*rstd*g[tid+256] + bta[tid+256];
  float y2 = (v2-mean)*rstd*g[tid+512] + bta[tid+512];
  if (outB){ outB[ob+tid]=(__bf16)y0; outB[ob+tid+256]=(__bf16)y1; outB[ob+tid+512]=(__bf16)y2; }
  else     { outF[ob+tid]=y0;         outF[ob+tid+256]=y1;         outF[ob+tid+512]=y2; }
}

// ---------------- MFMA attention: one block per (b,h), T=101 pad 112, HD=64 ----------------
// Phase A: S = Q@K^T (C/D-layout regs) -> softmax in regs -> P bf16 to LDS (A-layout)
// Phase B: O = P@V, V B-frags gathered from Vs via ds_read_u16 (stride-68 rows: 4-way max)

#define QKS 72    // Qs/Ks row stride (elements): 144B, 16B-aligned
#define PSS 136   // Ps row stride: 272B, 16B-aligned
#define VSS 68    // Vs row stride (scalar access only)

__global__ __launch_bounds__(256) void k_attn(const __bf16* __restrict__ qkvB, __bf16* __restrict__ o){
  __shared__ alignas(16) __bf16 smem[112*QKS*2 + 128*VSS];
  __bf16* Qs = smem;
  __bf16* Ks = smem + 112*QKS;
  __bf16* Vs = smem + 112*QKS*2;
  __bf16* Ps = smem;                    // overlays Qs+Ks: 112*136 <= 112*72*2
  int b = blockIdx.x / 12, h = blockIdx.x % 12;
  int tid = threadIdx.x;
  const __bf16* basep = qkvB + (size_t)(b*101)*2304 + h*64;
  for (int idx = tid; idx < 112*64; idx += 256){
    int t = idx >> 6, d = idx & 63;
    __bf16 qv = (__bf16)0.f, kv = (__bf16)0.f;
    if (t < 101){ qv = basep[(size_t)t*2304 + d]; kv = basep[(size_t)t*2304 + 768 + d]; }
    Qs[t*QKS + d] = qv; Ks[t*QKS + d] = kv;
  }
  for (int idx = tid; idx < 128*64; idx += 256){
    int t = idx >> 6, d = idx & 63;
    Vs[t*VSS + d] = (t < 101) ? basep[(size_t)t*2304 + 1536 + d] : (__bf16)0.f;
  }
  __syncthreads();
  int wave = tid >> 6, lane = tid & 63;
  int r16 = lane & 15, q = lane >> 4;
  int nt = (wave < 3) ? 2 : 1;          // waves 0-2: tiles {w, w+4}; wave 3: tile {3}
  f4 sacc[2][7];
  for (int rt = 0; rt < nt; rt++){
    int m0 = (wave + rt*4)*16;
    #pragma unroll
    for (int j = 0; j < 7; j++) sacc[rt][j] = (f4){0.f,0.f,0.f,0.f};
    #pragma unroll
    for (int kt = 0; kt < 64; kt += 32){
      bf8 af = *reinterpret_cast<const bf8*>(&Qs[(m0 + r16)*QKS + kt + q*8]);
      #pragma unroll
      for (int j = 0; j < 7; j++){
        bf8 bf = *reinterpret_cast<const bf8*>(&Ks[(j*16 + r16)*QKS + kt + q*8]);
        sacc[rt][j] = __builtin_amdgcn_mfma_f32_16x16x32_bf16(af, bf, sacc[rt][j], 0, 0, 0);
      }
    }
  }
  __syncthreads();                      // all phase-A LDS reads done; Ps may overwrite
  for (int rt = 0; rt < nt; rt++){
    int m0 = (wave + rt*4)*16;
    #pragma unroll
    for (int r = 0; r < 4; r++){
      float s[7];
      #pragma unroll
      for (int j = 0; j < 7; j++){
        s[j] = sacc[rt][j][r] * 0.125f;
        if (j == 6 && r16 >= 5) s[j] = -1e30f;   // cols 101..111 masked
      }
      float mx = s[0];
      #pragma unroll
      for (int j = 1; j < 7; j++) mx = fmaxf(mx, s[j]);
      #pragma unroll
      for (int off2 = 1; off2 < 16; off2 <<= 1) mx = fmaxf(mx, __shfl_xor(mx, off2));
      float p[7], sum = 0.f;
      #pragma unroll
      for (int j = 0; j < 7; j++){ p[j] = expf(s[j] - mx); sum += p[j]; }
      #pragma unroll
      for (int off2 = 1; off2 < 16; off2 <<= 1) sum += __shfl_xor(sum, off2);
      float inv = 1.f / sum;
      int row = m0 + q*4 + r;
      #pragma unroll
      for (int j = 0; j < 7; j++) Ps[row*PSS + j*16 + r16] = (__bf16)(p[j]*inv);
      Ps[row*PSS + 112 + r16] = (__bf16)0.f;     // zero k-pad cols 112..127
    }
  }
  __syncthreads();
  f4 oacc[2][4];
  #pragma unroll
  for (int rt = 0; rt < 2; rt++)
    #pragma unroll
    for (int n = 0; n < 4; n++) oacc[rt][n] = (f4){0.f,0.f,0.f,0.f};
  for (int kt = 0; kt < 128; kt += 32){
    bf8 af[2];
    for (int rt = 0; rt < nt; rt++)
      af[rt] = *reinterpret_cast<const bf8*>(&Ps[((wave + rt*4)*16 + r16)*PSS + kt + q*8]);
    #pragma unroll
    for (int n = 0; n < 4; n++){
      bf8 bq;
      #pragma unroll
      for (int ii = 0; ii < 8; ii++) bq[ii] = Vs[(kt + q*8 + ii)*VSS + n*16 + r16];
      for (int rt = 0; rt < nt; rt++)
        oacc[rt][n] = __builtin_amdgcn_mfma_f32_16x16x32_bf16(af[rt], bq, oacc[rt][n], 0, 0, 0);
    }
  }
  for (int rt = 0; rt < nt; rt++){
    int m0 = (wave + rt*4)*16;
    #pragma unroll
    for (int n = 0; n < 4; n++){
      #pragma unroll
      for (int r = 0; r < 4; r++){
        int t = m0 + q*4 + r;
        if (t < 101)
          o[((size_t)(b*101 + t))*768 + h*64 + n*16 + r16] = (__bf16)oacc[rt][n][r];
      }
    }
  }
}

__global__ void k_head(const float* __restrict__ cls, const float* __restrict__ hw,
                       const float* __restrict__ hb, float* __restrict__ out){
  int b = blockIdx.x, c = threadIdx.x;
  if (c < 40){
    float s = hb[c];
    for (int k = 0; k < 768; k++) s += cls[b*768 + k]*hw[k*40 + c];
    out[b*40 + c] = s;
  }
}

// ---------------- launch ----------------

extern "C" void kernel_launch(void* const* d_in, const int* in_sizes, int n_in,
                              void* d_out, int out_size, void* d_ws, size_t ws_size,
                              hipStream_t stream){
  const float* x       = (const float*)d_in[0];
  const float* W1      = (const float*)d_in[1];
  const float* W2      = (const float*)d_in[2];
  const float* W3      = (const float*)d_in[3];
  const float* Wa      = (const float*)d_in[4];
  const float* bn_g    = (const float*)d_in[5];
  const float* bn_b    = (const float*)d_in[6];
  const float* bn_mean = (const float*)d_in[7];
  const float* bn_var  = (const float*)d_in[8];
  const float* cls_t   = (const float*)d_in[9];
  const float* pos     = (const float*)d_in[10];
  const float* ln1_g   = (const float*)d_in[11];
  const float* ln1_b   = (const float*)d_in[12];
  const float* qkv_w   = (const float*)d_in[13];
  const float* proj_w  = (const float*)d_in[14];
  const float* proj_b  = (const float*)d_in[15];
  const float* ln2_g   = (const float*)d_in[16];
  const float* ln2_b   = (const float*)d_in[17];
  const float* fc1_w   = (const float*)d_in[18];
  const float* fc1_b   = (const float*)d_in[19];
  const float* fc2_w   = (const float*)d_in[20];
  const float* fc2_b   = (const float*)d_in[21];
  const float* norm_g  = (const float*)d_in[22];
  const float* norm_b  = (const float*)d_in[23];
  const float* head_w  = (const float*)d_in[24];
  const float* head_b  = (const float*)d_in[25];

  char* ws = (char*)d_ws;
  size_t off = 0;
  auto alloc = [&](size_t bytes)->void*{ void* p = ws + off; off += (bytes + 255) & ~(size_t)255; return p; };
  // --- persistent region ---
  float* cnt     = (float*)alloc(3200*4);
  float* cent    = (float*)alloc(3200*3*4);
  float* pillar  = (float*)alloc((size_t)3200*768*4);
  size_t zbytes  = (size_t)((char*)pillar - (char*)cnt) + (size_t)3200*768*4;
  int*   base    = (int*)  alloc(3200*4);
  int*   wptr    = (int*)  alloc(3200*4);
  int*   order   = (int*)  alloc((size_t)65536*4);
  int*   cellSlot= (int*)  alloc((size_t)65536*4);
  int*   cellArr = (int*)  alloc((size_t)65536*4);
  float* pooled  = (float*)alloc((size_t)3200*128*4);
  float* tokens  = (float*)alloc((size_t)3232*768*4);
  float* cls     = (float*)alloc((size_t)32*768*4);
  __bf16* wWa    = (__bf16*)alloc((size_t)768*256*2);
  // --- overlaid region R ---
  size_t offR = off;
  __bf16* A2  = (__bf16*)alloc((size_t)65536*256*2);
  __bf16* h2c = (__bf16*)alloc((size_t)16384*768*2);
  size_t endPillarPhase = off;
  off = offR;
  __bf16* y    = (__bf16*)alloc((size_t)3232*768*2);
  __bf16* qkvB = (__bf16*)alloc((size_t)3232*2304*2);
  __bf16* o    = (__bf16*)alloc((size_t)3232*768*2);
  __bf16* mlp  = (__bf16*)alloc((size_t)3232*3072*2);
  __bf16* wq   = (__bf16*)alloc((size_t)768*2304*2);
  __bf16* wp   = (__bf16*)alloc((size_t)768*768*2);
  __bf16* w1   = (__bf16*)alloc((size_t)768*3072*2);
  __bf16* w2   = (__bf16*)alloc((size_t)3072*768*2);
  if (off < endPillarPhase) off = endPillarPhase;
  (void)ws_size; (void)in_sizes; (void)n_in; (void)out_size;

  hipMemsetAsync(cnt, 0, zbytes, stream);

  // pillar feature stage
  k_cell<<<256,256,0,stream>>>(x, cellArr, cnt, cent);
  k_centdiv<<<38,256,0,stream>>>(cent, cnt);
  k_scan<<<1,256,0,stream>>>(cnt, base, wptr);
  k_scatter<<<256,256,0,stream>>>(cellArr, wptr, order);
  k_pointmlp<<<256,256,0,stream>>>(x, W1, W2, W3, cent, cellArr, order, cellSlot, A2);
  k_poolh<<<3200,128,0,stream>>>(A2, base, cnt, pooled);
  k_fill<<<32768,256,0,stream>>>(pooled, cellSlot, A2);
  k_transpose<<<dim3(24,8),256,0,stream>>>(Wa, wWa, 256, 768);
  for (int c = 0; c < 4; c++){
    k_gemm<<<dim3(6,128),256,0,stream>>>(A2 + (size_t)c*16384*256, wWa, nullptr, nullptr,
                                         nullptr, h2c, 16384, 768, 256, 1);
    k_pillarpool<<<3200,256,0,stream>>>(h2c, base, cnt, pillar, c*16384);
  }
  k_assemble<<<9696,256,0,stream>>>(pillar, bn_g, bn_b, bn_mean, bn_var, cls_t, pos, tokens);

  // transformer
  for (int l = 0; l < 12; l++){
    k_transpose_all<<<6912,256,0,stream>>>(qkv_w + (size_t)l*768*2304, proj_w + (size_t)l*768*768,
                                           fc1_w + (size_t)l*768*3072, fc2_w + (size_t)l*3072*768,
                                           wq, wp, w1, w2);
    k_ln<<<3232,256,0,stream>>>(tokens, ln1_g + l*768, ln1_b + l*768, y, nullptr, 1);
    k_gemm<<<dim3(18,26),256,0,stream>>>(y, wq, nullptr, nullptr, nullptr, qkvB, 3232, 2304, 768, 0);
    k_attn<<<384,256,0,stream>>>(qkvB, o);
    k_gemm<<<dim3(6,26),256,0,stream>>>(o, wp, proj_b + l*768, tokens, tokens, nullptr, 3232, 768, 768, 0);
    k_ln<<<3232,256,0,stream>>>(tokens, ln2_g + l*768, ln2_b + l*768, y, nullptr, 1);
    k_gemm<<<dim3(24,26),256,0,stream>>>(y, w1, fc1_b + l*3072, nullptr, nullptr, mlp, 3232, 3072, 768, 2);
    k_gemm<<<dim3(6,26),256,0,stream>>>(mlp, w2, fc2_b + l*768, tokens, tokens, nullptr, 3232, 768, 3072, 0);
  }

  k_ln<<<32,256,0,stream>>>(tokens, norm_g, norm_b, nullptr, cls, 101);
  k_head<<<32,64,0,stream>>>(cls, head_w, head_b, (float*)d_out);
}

// Round 4
// 3865.002 us; speedup vs baseline: 1.7233x; 1.1004x over previous
//
#include <hip/hip_runtime.h>

typedef __bf16 bf8 __attribute__((ext_vector_type(8)));
typedef float  f4  __attribute__((ext_vector_type(4)));
typedef unsigned long long uptr;

__device__ __forceinline__ void gload16(const void* g, void* l){
  __builtin_amdgcn_global_load_lds(
      (const __attribute__((address_space(1))) unsigned int*)(uptr)g,
      (__attribute__((address_space(3))) unsigned int*)(uptr)l,
      16, 0, 0);
}

// ---------------- pillar stage ----------------

__global__ __launch_bounds__(256) void k_cell(const float* __restrict__ x, int* __restrict__ cellArr,
                                              float* __restrict__ cnt, float* __restrict__ cent){
  int p = blockIdx.x*256 + threadIdx.x;            // 65536 points
  float x0 = x[p*3+0], x1 = x[p*3+1], x2 = x[p*3+2];
  float y0 = fminf(fmaxf(x0 + 1.0f, 0.0f), 1.99f);
  float y1 = fminf(fmaxf(x2 + 1.0f, 0.0f), 1.99f);
  int i0 = (int)floorf(y0 / 0.2f);
  int i1 = (int)floorf(y1 / 0.2f);
  int b = p >> 11;
  int cell = b*100 + i0*10 + i1;
  cellArr[p] = cell;
  atomicAdd(&cnt[cell], 1.0f);
  atomicAdd(&cent[cell*3+0], x1);
  atomicAdd(&cent[cell*3+1], x0);
  atomicAdd(&cent[cell*3+2], x2);
}

__global__ void k_centdiv(float* cent, const float* cnt){
  int i = blockIdx.x*256 + threadIdx.x;
  if (i < 3200*3) cent[i] /= fmaxf(cnt[i/3], 1.0f);
}

// counting-sort scan: base = exclusive prefix of cnt; wptr = copy of base
__global__ __launch_bounds__(256) void k_scan(const float* __restrict__ cnt,
                                              int* __restrict__ base, int* __restrict__ wptr){
  __shared__ int a[256];
  int tid = threadIdx.x;
  int start = tid*13, end = start+13; if (end > 3200) end = 3200;
  int local = 0;
  for (int i = start; i < end; i++) local += (int)cnt[i];
  a[tid] = local;
  __syncthreads();
  for (int off = 1; off < 256; off <<= 1){
    int t = (tid >= off) ? a[tid - off] : 0;
    __syncthreads();
    a[tid] += t;
    __syncthreads();
  }
  int run = a[tid] - local;
  for (int i = start; i < end; i++){
    base[i] = run; wptr[i] = run;
    run += (int)cnt[i];
  }
}

__global__ __launch_bounds__(256) void k_scatter(const int* __restrict__ cellArr,
                                                 int* __restrict__ wptr, int* __restrict__ order){
  int p = blockIdx.x*256 + threadIdx.x;
  int c = cellArr[p];
  int pos = atomicAdd(&wptr[c], 1);
  order[pos] = p;
}

__global__ __launch_bounds__(256) void k_pointmlp(const float* __restrict__ x,
    const float* __restrict__ W1, const float* __restrict__ W2, const float* __restrict__ W3,
    const float* __restrict__ cent, const int* __restrict__ cellArr,
    const int* __restrict__ order, int* __restrict__ cellSlot, __bf16* __restrict__ A2){
  __shared__ float w1s[6*32];
  __shared__ float w2s[32*64];
  __shared__ float w3s[64*128];
  int tid = threadIdx.x;
  for (int i = tid; i < 192;  i += 256) w1s[i] = W1[i];
  for (int i = tid; i < 2048; i += 256) w2s[i] = W2[i];
  for (int i = tid; i < 8192; i += 256) w3s[i] = W3[i];
  __syncthreads();
  int s = blockIdx.x*256 + tid;                 // sorted slot
  int p = order[s];
  int cell = cellArr[p];
  cellSlot[s] = cell;
  float pf0 = x[p*3+1], pf1 = x[p*3+0], pf2 = x[p*3+2];
  float a[6] = {pf0, pf1, pf2, pf0 - cent[cell*3+0], pf1 - cent[cell*3+1], pf2 - cent[cell*3+2]};
  float h1[32];
  #pragma unroll
  for (int f = 0; f < 32; f++){
    float t = 0.f;
    #pragma unroll
    for (int i = 0; i < 6; i++) t += a[i]*w1s[i*32+f];
    h1[f] = fmaxf(t, 0.f);
  }
  float h2[64];
  #pragma unroll
  for (int f = 0; f < 64; f++){
    float t = 0.f;
    #pragma unroll
    for (int i = 0; i < 32; i++) t += h1[i]*w2s[i*64+f];
    h2[f] = fmaxf(t, 0.f);
  }
  for (int f0 = 0; f0 < 128; f0 += 8){
    __bf16 tmp[8];
    #pragma unroll
    for (int j = 0; j < 8; j++){
      float t = 0.f;
      #pragma unroll
      for (int i = 0; i < 64; i++) t += h2[i]*w3s[i*128+f0+j];
      tmp[j] = (__bf16)fmaxf(t, 0.f);
    }
    *reinterpret_cast<uint4*>(&A2[(size_t)s*256 + f0]) = *reinterpret_cast<uint4*>(tmp);
  }
}

__global__ __launch_bounds__(128) void k_poolh(const __bf16* __restrict__ A2,
    const int* __restrict__ base, const float* __restrict__ cnt, float* __restrict__ pooled){
  int c = blockIdx.x, f = threadIdx.x;
  int b0 = base[c], n = (int)cnt[c];
  float v = 0.f;
  for (int k = 0; k < n; k++) v = fmaxf(v, (float)A2[(size_t)(b0+k)*256 + f]);
  pooled[c*128 + f] = v;
}

__global__ __launch_bounds__(256) void k_fill(const float* __restrict__ pooled,
    const int* __restrict__ cellSlot, __bf16* __restrict__ A2){
  int idx = blockIdx.x*256 + threadIdx.x;       // 65536*128
  int s = idx >> 7, f = idx & 127;
  A2[(size_t)s*256 + 128 + f] = (__bf16)pooled[cellSlot[s]*128 + f];
}

__global__ __launch_bounds__(256) void k_pillarpool(const __bf16* __restrict__ h2c,
    const int* __restrict__ base, const float* __restrict__ cnt, float* __restrict__ pillar, int cs){
  int c = blockIdx.x, tid = threadIdx.x;
  int b0 = base[c], e0 = b0 + (int)cnt[c];
  int lo = b0 > cs ? b0 : cs;
  int hi = e0 < cs + 16384 ? e0 : cs + 16384;
  if (lo >= hi) return;
  for (int f = tid; f < 768; f += 256){
    float v = 0.f;
    for (int s = lo; s < hi; s++) v = fmaxf(v, (float)h2c[(size_t)(s - cs)*768 + f]);
    atomicMax((int*)&pillar[(size_t)c*768 + f], __float_as_int(v));
  }
}

__global__ void k_assemble(const float* __restrict__ pillar,
    const float* __restrict__ bn_g, const float* __restrict__ bn_b,
    const float* __restrict__ bn_mean, const float* __restrict__ bn_var,
    const float* __restrict__ cls_t, const float* __restrict__ pos,
    float* __restrict__ tokens){
  int idx = blockIdx.x*256 + threadIdx.x;          // 3232*768
  int m = idx / 768, d = idx % 768;
  int b = m / 101, t = m % 101;
  float v;
  if (t == 0) v = cls_t[d];
  else {
    int s = t - 1;
    float pv = pillar[((size_t)b*100 + s)*768 + d];
    float inv = bn_g[s]*rsqrtf(bn_var[s] + 1e-5f);
    v = (pv - bn_mean[s])*inv + bn_b[s];
  }
  tokens[idx] = v + pos[t*768 + d];
}

// ---------------- weight transpose-convert ----------------

__global__ __launch_bounds__(256) void k_transpose(const float* __restrict__ W, __bf16* __restrict__ Wt,
                                                   int K, int N){
  __shared__ float t[32][33];
  int n0 = blockIdx.x*32, k0 = blockIdx.y*32;
  int tx = threadIdx.x & 31, ty = threadIdx.x >> 5;
  #pragma unroll
  for (int i = 0; i < 32; i += 8){
    int k = k0 + ty + i, n = n0 + tx;
    t[ty+i][tx] = (k < K && n < N) ? W[(size_t)k*N + n] : 0.f;
  }
  __syncthreads();
  #pragma unroll
  for (int i = 0; i < 32; i += 8){
    int n = n0 + ty + i, k = k0 + tx;
    if (n < N && k < K) Wt[(size_t)n*K + k] = (__bf16)t[tx][ty+i];
  }
}

__global__ __launch_bounds__(256) void k_transpose_all(
    const float* __restrict__ qw, const float* __restrict__ pw,
    const float* __restrict__ f1, const float* __restrict__ f2,
    __bf16* __restrict__ wq, __bf16* __restrict__ wp,
    __bf16* __restrict__ w1, __bf16* __restrict__ w2){
  int id = blockIdx.x;
  const float* W; __bf16* Wt; int K, N, nx, ny;
  if (id < 1728){ W=qw; Wt=wq; K=768;  N=2304; nx=id%72; ny=id/72; }
  else if (id < 2304){ id-=1728; W=pw; Wt=wp; K=768;  N=768;  nx=id%24; ny=id/24; }
  else if (id < 4608){ id-=2304; W=f1; Wt=w1; K=768;  N=3072; nx=id%96; ny=id/96; }
  else {               id-=4608; W=f2; Wt=w2; K=3072; N=768;  nx=id%24; ny=id/24; }
  __shared__ float t[32][33];
  int n0 = nx*32, k0 = ny*32;
  int tx = threadIdx.x & 31, ty = threadIdx.x >> 5;
  #pragma unroll
  for (int i = 0; i < 32; i += 8) t[ty+i][tx] = W[(size_t)(k0+ty+i)*N + n0+tx];
  __syncthreads();
  #pragma unroll
  for (int i = 0; i < 32; i += 8) Wt[(size_t)(n0+ty+i)*K + k0+tx] = (__bf16)t[tx][ty+i];
}

// ---------------- bf16 MFMA GEMM (m97-style global_load_lds staging) ----------------
// C[M][N] = A[M][K] @ Bt[N][K]^T ; act: 0 none, 1 relu, 2 gelu(exact)
// splitK > 1: grid.z = splitK, fp32 atomicAdd into outF (which pre-holds the
// residual); bias added by the z==0 split only; act must be 0.

__global__ __launch_bounds__(256) void k_gemm(const __bf16* __restrict__ A, const __bf16* __restrict__ Bt,
    const float* __restrict__ bias, const float* __restrict__ res,
    float* __restrict__ outF, __bf16* __restrict__ outB,
    int M, int N, int K, int act, int splitK){
  __shared__ alignas(16) __bf16 As[128*32];
  __shared__ alignas(16) __bf16 Bs[128*32];
  int tid  = threadIdx.x;
  int m0 = blockIdx.y*128, n0 = blockIdx.x*128;
  int z = blockIdx.z;
  int kLen = K / splitK, k0 = z*kLen;
  int wave = tid >> 6, lane = tid & 63;
  int wm = (wave >> 1)*64, wn = (wave & 1)*64;
  int r16 = lane & 15, q = lane >> 4;
  int lrow = lane >> 2, lpc = lane & 3;
  f4 acc[4][4];
  #pragma unroll
  for (int i = 0; i < 4; i++)
    #pragma unroll
    for (int j = 0; j < 4; j++) acc[i][j] = (f4){0.f,0.f,0.f,0.f};

  for (int kt = k0; kt < k0 + kLen; kt += 32){
    #pragma unroll
    for (int s = 0; s < 2; s++){
      int rg  = wave*2 + s;
      int row = rg*16 + lrow;
      int gm = m0 + row; if (gm >= M) gm = M - 1;
      gload16(A  + (size_t)gm*K + kt + lpc*8, (char*)As + rg*1024 + lane*16);
      int gn = n0 + row;
      gload16(Bt + (size_t)gn*K + kt + lpc*8, (char*)Bs + rg*1024 + lane*16);
    }
    __syncthreads();
    bf8 af[4], bq[4];
    #pragma unroll
    for (int i = 0; i < 4; i++) af[i] = *reinterpret_cast<const bf8*>(&As[(wm + i*16 + r16)*32 + q*8]);
    #pragma unroll
    for (int j = 0; j < 4; j++) bq[j] = *reinterpret_cast<const bf8*>(&Bs[(wn + j*16 + r16)*32 + q*8]);
    #pragma unroll
    for (int i = 0; i < 4; i++)
      #pragma unroll
      for (int j = 0; j < 4; j++)
        acc[i][j] = __builtin_amdgcn_mfma_f32_16x16x32_bf16(af[i], bq[j], acc[i][j], 0, 0, 0);
    __syncthreads();
  }

  #pragma unroll
  for (int i = 0; i < 4; i++){
    #pragma unroll
    for (int j = 0; j < 4; j++){
      int nn = n0 + wn + j*16 + r16;
      float bv = (bias && z == 0) ? bias[nn] : 0.f;
      #pragma unroll
      for (int r = 0; r < 4; r++){
        int m = m0 + wm + i*16 + q*4 + r;
        if (m >= M) continue;
        float v = acc[i][j][r] + bv;
        if (splitK > 1){
          atomicAdd(&outF[(size_t)m*N + nn], v);
        } else {
          if (act == 1) v = fmaxf(v, 0.f);
          else if (act == 2) v = 0.5f*v*(1.f + erff(v*0.70710678118654752f));
          if (outB){
            outB[(size_t)m*N + nn] = (__bf16)v;
          } else {
            float rv = res ? res[(size_t)m*N + nn] : 0.f;
            outF[(size_t)m*N + nn] = rv + v;
          }
        }
      }
    }
  }
}

// ---------------- layernorm (row = 768) ----------------

__global__ __launch_bounds__(256) void k_ln(const float* __restrict__ in, const float* __restrict__ g,
    const float* __restrict__ bta, __bf16* __restrict__ outB, float* __restrict__ outF, int rowMul){
  int orow = blockIdx.x;
  const float* xr = in + (size_t)orow*rowMul*768;
  int tid = threadIdx.x;
  float v0 = xr[tid], v1 = xr[tid+256], v2 = xr[tid+512];
  float s = v0+v1+v2, s2 = v0*v0 + v1*v1 + v2*v2;
  #pragma unroll
  for (int off = 32; off > 0; off >>= 1){ s += __shfl_xor(s, off); s2 += __shfl_xor(s2, off); }
  __shared__ float rs[4], rq[4];
  int w = tid >> 6;
  if ((tid & 63) == 0){ rs[w] = s; rq[w] = s2; }
  __syncthreads();
  s = rs[0]+rs[1]+rs[2]+rs[3]; s2 = rq[0]+rq[1]+rq[2]+rq[3];
  float mean = s*(1.f/768.f);
  float var  = s2*(1.f/768.f) - mean*mean;
  float rstd = rsqrtf(var + 1e-5f);
  size_t ob = (size_t)orow*768;
  float y0 = (v0-mean)*rstd*g[tid]     + bta[tid];
  float y1 = (v1-mean)*rstd*g[tid+256] + bta[tid+256];
  float y2 = (v2-mean)*rstd*g[tid+512] + bta[tid+512];
  if (outB){ outB[ob+tid]=(__bf16)y0; outB[ob+tid+256]=(__bf16)y1; outB[ob+tid+512]=(__bf16)y2; }
  else     { outF[ob+tid]=y0;         outF[ob+tid+256]=y1;         outF[ob+tid+512]=y2; }
}

// ---------------- MFMA attention: one block per (b,h), T=101 pad 112, HD=64 ----------------

#define QKS 72    // Qs/Ks row stride (elements): 144B, 16B-aligned
#define PSS 136   // Ps row stride: 272B, 16B-aligned
#define VSS 68    // Vs row stride (scalar access only)

__global__ __launch_bounds__(256) void k_attn(const __bf16* __restrict__ qkvB, __bf16* __restrict__ o){
  __shared__ alignas(16) __bf16 smem[112*QKS*2 + 128*VSS];
  __bf16* Qs = smem;
  __bf16* Ks = smem + 112*QKS;
  __bf16* Vs = smem + 112*QKS*2;
  __bf16* Ps = smem;                    // overlays Qs+Ks
  int b = blockIdx.x / 12, h = blockIdx.x % 12;
  int tid = threadIdx.x;
  const __bf16* basep = qkvB + (size_t)(b*101)*2304 + h*64;
  for (int idx = tid; idx < 112*64; idx += 256){
    int t = idx >> 6, d = idx & 63;
    __bf16 qv = (__bf16)0.f, kv = (__bf16)0.f;
    if (t < 101){ qv = basep[(size_t)t*2304 + d]; kv = basep[(size_t)t*2304 + 768 + d]; }
    Qs[t*QKS + d] = qv; Ks[t*QKS + d] = kv;
  }
  for (int idx = tid; idx < 128*64; idx += 256){
    int t = idx >> 6, d = idx & 63;
    Vs[t*VSS + d] = (t < 101) ? basep[(size_t)t*2304 + 1536 + d] : (__bf16)0.f;
  }
  __syncthreads();
  int wave = tid >> 6, lane = tid & 63;
  int r16 = lane & 15, q = lane >> 4;
  int nt = (wave < 3) ? 2 : 1;
  f4 sacc[2][7];
  for (int rt = 0; rt < nt; rt++){
    int m0 = (wave + rt*4)*16;
    #pragma unroll
    for (int j = 0; j < 7; j++) sacc[rt][j] = (f4){0.f,0.f,0.f,0.f};
    #pragma unroll
    for (int kt = 0; kt < 64; kt += 32){
      bf8 af = *reinterpret_cast<const bf8*>(&Qs[(m0 + r16)*QKS + kt + q*8]);
      #pragma unroll
      for (int j = 0; j < 7; j++){
        bf8 bf = *reinterpret_cast<const bf8*>(&Ks[(j*16 + r16)*QKS + kt + q*8]);
        sacc[rt][j] = __builtin_amdgcn_mfma_f32_16x16x32_bf16(af, bf, sacc[rt][j], 0, 0, 0);
      }
    }
  }
  __syncthreads();
  for (int rt = 0; rt < nt; rt++){
    int m0 = (wave + rt*4)*16;
    #pragma unroll
    for (int r = 0; r < 4; r++){
      float s[7];
      #pragma unroll
      for (int j = 0; j < 7; j++){
        s[j] = sacc[rt][j][r] * 0.125f;
        if (j == 6 && r16 >= 5) s[j] = -1e30f;
      }
      float mx = s[0];
      #pragma unroll
      for (int j = 1; j < 7; j++) mx = fmaxf(mx, s[j]);
      #pragma unroll
      for (int off2 = 1; off2 < 16; off2 <<= 1) mx = fmaxf(mx, __shfl_xor(mx, off2));
      float p[7], sum = 0.f;
      #pragma unroll
      for (int j = 0; j < 7; j++){ p[j] = expf(s[j] - mx); sum += p[j]; }
      #pragma unroll
      for (int off2 = 1; off2 < 16; off2 <<= 1) sum += __shfl_xor(sum, off2);
      float inv = 1.f / sum;
      int row = m0 + q*4 + r;
      #pragma unroll
      for (int j = 0; j < 7; j++) Ps[row*PSS + j*16 + r16] = (__bf16)(p[j]*inv);
      Ps[row*PSS + 112 + r16] = (__bf16)0.f;
    }
  }
  __syncthreads();
  f4 oacc[2][4];
  #pragma unroll
  for (int rt = 0; rt < 2; rt++)
    #pragma unroll
    for (int n = 0; n < 4; n++) oacc[rt][n] = (f4){0.f,0.f,0.f,0.f};
  for (int kt = 0; kt < 128; kt += 32){
    bf8 af[2];
    for (int rt = 0; rt < nt; rt++)
      af[rt] = *reinterpret_cast<const bf8*>(&Ps[((wave + rt*4)*16 + r16)*PSS + kt + q*8]);
    #pragma unroll
    for (int n = 0; n < 4; n++){
      bf8 bq;
      #pragma unroll
      for (int ii = 0; ii < 8; ii++) bq[ii] = Vs[(kt + q*8 + ii)*VSS + n*16 + r16];
      for (int rt = 0; rt < nt; rt++)
        oacc[rt][n] = __builtin_amdgcn_mfma_f32_16x16x32_bf16(af[rt], bq, oacc[rt][n], 0, 0, 0);
    }
  }
  for (int rt = 0; rt < nt; rt++){
    int m0 = (wave + rt*4)*16;
    #pragma unroll
    for (int n = 0; n < 4; n++){
      #pragma unroll
      for (int r = 0; r < 4; r++){
        int t = m0 + q*4 + r;
        if (t < 101)
          o[((size_t)(b*101 + t))*768 + h*64 + n*16 + r16] = (__bf16)oacc[rt][n][r];
      }
    }
  }
}

__global__ void k_head(const float* __restrict__ cls, const float* __restrict__ hw,
                       const float* __restrict__ hb, float* __restrict__ out){
  int b = blockIdx.x, c = threadIdx.x;
  if (c < 40){
    float s = hb[c];
    for (int k = 0; k < 768; k++) s += cls[b*768 + k]*hw[k*40 + c];
    out[b*40 + c] = s;
  }
}

// ---------------- launch ----------------

extern "C" void kernel_launch(void* const* d_in, const int* in_sizes, int n_in,
                              void* d_out, int out_size, void* d_ws, size_t ws_size,
                              hipStream_t stream){
  const float* x       = (const float*)d_in[0];
  const float* W1      = (const float*)d_in[1];
  const float* W2      = (const float*)d_in[2];
  const float* W3      = (const float*)d_in[3];
  const float* Wa      = (const float*)d_in[4];
  const float* bn_g    = (const float*)d_in[5];
  const float* bn_b    = (const float*)d_in[6];
  const float* bn_mean = (const float*)d_in[7];
  const float* bn_var  = (const float*)d_in[8];
  const float* cls_t   = (const float*)d_in[9];
  const float* pos     = (const float*)d_in[10];
  const float* ln1_g   = (const float*)d_in[11];
  const float* ln1_b   = (const float*)d_in[12];
  const float* qkv_w   = (const float*)d_in[13];
  const float* proj_w  = (const float*)d_in[14];
  const float* proj_b  = (const float*)d_in[15];
  const float* ln2_g   = (const float*)d_in[16];
  const float* ln2_b   = (const float*)d_in[17];
  const float* fc1_w   = (const float*)d_in[18];
  const float* fc1_b   = (const float*)d_in[19];
  const float* fc2_w   = (const float*)d_in[20];
  const float* fc2_b   = (const float*)d_in[21];
  const float* norm_g  = (const float*)d_in[22];
  const float* norm_b  = (const float*)d_in[23];
  const float* head_w  = (const float*)d_in[24];
  const float* head_b  = (const float*)d_in[25];

  char* ws = (char*)d_ws;
  size_t off = 0;
  auto alloc = [&](size_t bytes)->void*{ void* p = ws + off; off += (bytes + 255) & ~(size_t)255; return p; };
  // --- persistent region ---
  float* cnt     = (float*)alloc(3200*4);
  float* cent    = (float*)alloc(3200*3*4);
  float* pillar  = (float*)alloc((size_t)3200*768*4);
  size_t zbytes  = (size_t)((char*)pillar - (char*)cnt) + (size_t)3200*768*4;
  int*   base    = (int*)  alloc(3200*4);
  int*   wptr    = (int*)  alloc(3200*4);
  int*   order   = (int*)  alloc((size_t)65536*4);
  int*   cellSlot= (int*)  alloc((size_t)65536*4);
  int*   cellArr = (int*)  alloc((size_t)65536*4);
  float* pooled  = (float*)alloc((size_t)3200*128*4);
  float* tokens  = (float*)alloc((size_t)3232*768*4);
  float* cls     = (float*)alloc((size_t)32*768*4);
  __bf16* wWa    = (__bf16*)alloc((size_t)768*256*2);
  // --- overlaid region R ---
  size_t offR = off;
  __bf16* A2  = (__bf16*)alloc((size_t)65536*256*2);
  __bf16* h2c = (__bf16*)alloc((size_t)16384*768*2);
  size_t endPillarPhase = off;
  off = offR;
  __bf16* y    = (__bf16*)alloc((size_t)3232*768*2);
  __bf16* qkvB = (__bf16*)alloc((size_t)3232*2304*2);
  __bf16* o    = (__bf16*)alloc((size_t)3232*768*2);
  __bf16* mlp  = (__bf16*)alloc((size_t)3232*3072*2);
  __bf16* wq   = (__bf16*)alloc((size_t)768*2304*2);
  __bf16* wp   = (__bf16*)alloc((size_t)768*768*2);
  __bf16* w1   = (__bf16*)alloc((size_t)768*3072*2);
  __bf16* w2   = (__bf16*)alloc((size_t)3072*768*2);
  if (off < endPillarPhase) off = endPillarPhase;
  (void)ws_size; (void)in_sizes; (void)n_in; (void)out_size;

  hipMemsetAsync(cnt, 0, zbytes, stream);

  // pillar feature stage
  k_cell<<<256,256,0,stream>>>(x, cellArr, cnt, cent);
  k_centdiv<<<38,256,0,stream>>>(cent, cnt);
  k_scan<<<1,256,0,stream>>>(cnt, base, wptr);
  k_scatter<<<256,256,0,stream>>>(cellArr, wptr, order);
  k_pointmlp<<<256,256,0,stream>>>(x, W1, W2, W3, cent, cellArr, order, cellSlot, A2);
  k_poolh<<<3200,128,0,stream>>>(A2, base, cnt, pooled);
  k_fill<<<32768,256,0,stream>>>(pooled, cellSlot, A2);
  k_transpose<<<dim3(24,8),256,0,stream>>>(Wa, wWa, 256, 768);
  for (int c = 0; c < 4; c++){
    k_gemm<<<dim3(6,128),256,0,stream>>>(A2 + (size_t)c*16384*256, wWa, nullptr, nullptr,
                                         nullptr, h2c, 16384, 768, 256, 1, 1);
    k_pillarpool<<<3200,256,0,stream>>>(h2c, base, cnt, pillar, c*16384);
  }
  k_assemble<<<9696,256,0,stream>>>(pillar, bn_g, bn_b, bn_mean, bn_var, cls_t, pos, tokens);

  // transformer
  for (int l = 0; l < 12; l++){
    k_transpose_all<<<6912,256,0,stream>>>(qkv_w + (size_t)l*768*2304, proj_w + (size_t)l*768*768,
                                           fc1_w + (size_t)l*768*3072, fc2_w + (size_t)l*3072*768,
                                           wq, wp, w1, w2);
    k_ln<<<3232,256,0,stream>>>(tokens, ln1_g + l*768, ln1_b + l*768, y, nullptr, 1);
    k_gemm<<<dim3(18,26),256,0,stream>>>(y, wq, nullptr, nullptr, nullptr, qkvB, 3232, 2304, 768, 0, 1);
    k_attn<<<384,256,0,stream>>>(qkvB, o);
    // proj: split-K=4, atomic += into tokens (tokens already holds residual h)
    k_gemm<<<dim3(6,26,4),256,0,stream>>>(o, wp, proj_b + l*768, nullptr, tokens, nullptr,
                                          3232, 768, 768, 0, 4);
    k_ln<<<3232,256,0,stream>>>(tokens, ln2_g + l*768, ln2_b + l*768, y, nullptr, 1);
    k_gemm<<<dim3(24,26),256,0,stream>>>(y, w1, fc1_b + l*3072, nullptr, nullptr, mlp, 3232, 3072, 768, 2, 1);
    // fc2: split-K=4, atomic += into tokens
    k_gemm<<<dim3(6,26,4),256,0,stream>>>(mlp, w2, fc2_b + l*768, nullptr, tokens, nullptr,
                                          3232, 768, 3072, 0, 4);
  }

  k_ln<<<32,256,0,stream>>>(tokens, norm_g, norm_b, nullptr, cls, 101);
  k_head<<<32,64,0,stream>>>(cls, head_w, head_b, (float*)d_out);
}